// Round 7
// baseline (272.181 us; speedup 1.0000x reference)
//
#include <hip/hip_runtime.h>

#define S_LEN 256
#define B_SZ  512
#define T_TAGS 128
#define TP2   130
#define PAD_I (-1)

#define FWD_BLOCKS 32
#define NQ 32
#define QLEN 8
#define NSUB 8                       // 8 sub-blocks of 64 threads per s-chunk
#define NUM_BLOCKS (NQ * NSUB)       // 256
#define TOT_BLOCKS (FWD_BLOCKS + NUM_BLOCKS)
#define NTHR 64

typedef __bf16 bf16x8 __attribute__((ext_vector_type(8)));
typedef float  f32x4  __attribute__((ext_vector_type(4)));

// logical k-slot (c,lg,e) -> physical src-tag j. Chosen so D(C-layout) -> next B-fragment
// is same-lane: B slot (c,lg,e) = D[jt=2c+(e>>2)] reg r=(e&3) of the SAME lane.
#define PI_J(c, lg, e) ((2*(c) + ((e) >> 2))*16 + (lg)*4 + ((e) & 3))

// One fwd step, phase PH = s&3 (compile-time so raw/ee indices are static).
// raw ring: loads for step s+3 issued now; exp of raw[(s+1)&3] -> ee[(s+1)&1];
// consume ee[s&1]. Rescale on PH==0.
template<int PH>
__device__ __forceinline__ void fwd_step(
    int s, const float* __restrict__ em, const int* __restrict__ tags,
    int b0, int lm, int lg,
    const bf16x8 (&A)[8][4], bf16x8 (&Q)[4], float &M,
    f32x4 (&raw)[4][8], f32x4 (&ee)[2][8],
    int &tgA, int &tgB, int &tgC)
{
    // issue loads em[s+3] -> raw[(PH+3)&3]  (clamped; harmless dup at tail)
    const int sl = (s + 3 < S_LEN) ? (s + 3) : (S_LEN - 1);
    const float* ldp = &em[((size_t)sl * B_SZ + b0 + lm) * T_TAGS + lg * 4];
    #pragma unroll
    for (int q = 0; q < 8; ++q)
        raw[(PH + 3) & 3][q] = *(const f32x4*)&ldp[q * 16];
    const int tgD = tags[sl * B_SZ + b0 + lm];

    // D[jt] = E^T x Q  (8 independent 4-deep MFMA chains)
    f32x4 d[8];
    const f32x4 z = {0.f, 0.f, 0.f, 0.f};
    #pragma unroll
    for (int jt = 0; jt < 8; ++jt) {
        d[jt] = __builtin_amdgcn_mfma_f32_16x16x32_bf16(A[jt][0], Q[0], z, 0, 0, 0);
        #pragma unroll
        for (int c = 1; c < 4; ++c)
            d[jt] = __builtin_amdgcn_mfma_f32_16x16x32_bf16(A[jt][c], Q[c], d[jt], 0, 0, 0);
    }

    // exp pipeline for NEXT step: ee[(PH+1)&1] = exp(raw[(PH+1)&3])
    // (independent of the MFMA chain - fills dep-stall slots)
    #pragma unroll
    for (int q = 0; q < 8; ++q) {
        const f32x4 v = raw[(PH + 1) & 3][q];
        f32x4 w;
        #pragma unroll
        for (int r = 0; r < 4; ++r) w[r] = __expf(v[r]);
        ee[(PH + 1) & 1][q] = w;
    }

    // u = d * exp(em[s])
    float u[8][4];
    #pragma unroll
    for (int jt = 0; jt < 8; ++jt) {
        const f32x4 e4 = ee[PH & 1][jt];
        #pragma unroll
        for (int r = 0; r < 4; ++r) u[jt][r] = d[jt][r] * e4[r];
    }

    // amortized rescale every 4 steps; invariant lp = M + log P
    float Mn = M;
    if (PH == 0) {
        float R = u[0][0];
        #pragma unroll
        for (int jt = 0; jt < 8; ++jt)
            #pragma unroll
            for (int r = 0; r < 4; ++r) R = fmaxf(R, u[jt][r]);
        R = fmaxf(R, __shfl_xor(R, 16));
        R = fmaxf(R, __shfl_xor(R, 32));
        const float rr = 1.0f / R;
        Mn = M + __logf(R);
        #pragma unroll
        for (int jt = 0; jt < 8; ++jt)
            #pragma unroll
            for (int r = 0; r < 4; ++r) u[jt][r] *= rr;
    }

    // pack to next B-fragments (same-lane via PI_J); keep old state on PAD
    bf16x8 Qn[4];
    #pragma unroll
    for (int c = 0; c < 4; ++c)
        #pragma unroll
        for (int e = 0; e < 8; ++e)
            Qn[c][e] = (__bf16)u[2*c + (e >> 2)][e & 3];
    const bool live = (tgA != PAD_I);
    M = live ? Mn : M;
    #pragma unroll
    for (int c = 0; c < 4; ++c) Q[c] = live ? Qn[c] : Q[c];

    tgA = tgB; tgB = tgC; tgC = tgD;
}

__global__ __launch_bounds__(NTHR, 1) void crf_main(
    const float* __restrict__ em,     // (S,B,T)
    const float* __restrict__ trans,  // (T+2,T+2)
    const int*   __restrict__ tags,   // (S,B)
    float* __restrict__ denom_out,    // (B)
    float* __restrict__ pl,           // (NQ,B)
    int*   __restrict__ pc,           // (NQ,B)
    unsigned int* __restrict__ counter,
    float* __restrict__ out)
{
    const int t = threadIdx.x;

    if (blockIdx.x < FWD_BLOCKS) {
        // ---- single-wave forward chain: 16 batch rows, no LDS, no barriers ----
        const int lm = t & 15;
        const int lg = t >> 4;        // 0..3
        const int b0 = blockIdx.x * 16;

        bf16x8 A[8][4];               // E^T fragments (permuted k), resident forever
        #pragma unroll
        for (int jt = 0; jt < 8; ++jt)
            #pragma unroll
            for (int c = 0; c < 4; ++c)
                #pragma unroll
                for (int e = 0; e < 8; ++e)
                    A[jt][c][e] = (__bf16)__expf(trans[PI_J(c, lg, e)*TP2 + jt*16 + lm]);

        // Q init: P_1 = exp(trans[start][j] + em[0][b][j]), M = 0
        f32x4 em0[8];
        #pragma unroll
        for (int jt = 0; jt < 8; ++jt)
            em0[jt] = *(const f32x4*)&em[((size_t)0*B_SZ + b0 + lm)*T_TAGS + jt*16 + lg*4];
        bf16x8 Q[4];
        #pragma unroll
        for (int c = 0; c < 4; ++c)
            #pragma unroll
            for (int e = 0; e < 8; ++e) {
                const int j  = PI_J(c, lg, e);
                const int jt = 2*c + (e >> 2);
                const int r  = e & 3;
                Q[c][e] = (__bf16)__expf(trans[T_TAGS*TP2 + j] + em0[jt][r]);
            }
        float M = 0.f;

        // prologue: raw[1..3] <- em[1..3]; ee[1] = exp(raw[1]); tags 1..3
        f32x4 raw[4][8];
        f32x4 ee[2][8];
        #pragma unroll
        for (int sp = 1; sp <= 3; ++sp) {
            const float* ldp = &em[((size_t)sp*B_SZ + b0 + lm)*T_TAGS + lg*4];
            #pragma unroll
            for (int q = 0; q < 8; ++q)
                raw[sp][q] = *(const f32x4*)&ldp[q * 16];
        }
        #pragma unroll
        for (int q = 0; q < 8; ++q) {
            f32x4 w;
            #pragma unroll
            for (int r = 0; r < 4; ++r) w[r] = __expf(raw[1][q][r]);
            ee[1][q] = w;
        }
        int tgA = tags[1*B_SZ + b0 + lm];
        int tgB = tags[2*B_SZ + b0 + lm];
        int tgC = tags[3*B_SZ + b0 + lm];

        // steps 1..252 (63 x 4), then 253..255
        for (int s = 1; s <= S_LEN - 7; s += 4) {
            fwd_step<1>(s,     em, tags, b0, lm, lg, A, Q, M, raw, ee, tgA, tgB, tgC);
            fwd_step<2>(s + 1, em, tags, b0, lm, lg, A, Q, M, raw, ee, tgA, tgB, tgC);
            fwd_step<3>(s + 2, em, tags, b0, lm, lg, A, Q, M, raw, ee, tgA, tgB, tgC);
            fwd_step<0>(s + 3, em, tags, b0, lm, lg, A, Q, M, raw, ee, tgA, tgB, tgC);
        }
        fwd_step<1>(S_LEN - 3, em, tags, b0, lm, lg, A, Q, M, raw, ee, tgA, tgB, tgC);
        fwd_step<2>(S_LEN - 2, em, tags, b0, lm, lg, A, Q, M, raw, ee, tgA, tgB, tgC);
        fwd_step<3>(S_LEN - 1, em, tags, b0, lm, lg, A, Q, M, raw, ee, tgA, tgB, tgC);

        // epilogue: denom[b] = M + log(sum_j P[j]*exp(tend[j]))
        float sum = 0.f;
        #pragma unroll
        for (int c = 0; c < 4; ++c)
            #pragma unroll
            for (int e = 0; e < 8; ++e)
                sum += (float)Q[c][e] * __expf(trans[PI_J(c, lg, e)*TP2 + (T_TAGS + 1)]);
        sum += __shfl_xor(sum, 16);
        sum += __shfl_xor(sum, 32);
        if (t < 16)
            denom_out[b0 + t] = M + __logf(sum);
    } else {
        // ---------------- numerator partials ----------------
        const int nb = blockIdx.x - FWD_BLOCKS;   // 0..255
        const int q  = nb >> 3;                   // s-chunk 0..31
        const int b  = (nb & 7) * NTHR + t;
        const int s0 = q * QLEN;

        int tg[QLEN + 1];
        tg[0] = (s0 == 0) ? PAD_I : tags[(s0 - 1)*B_SZ + b];
        #pragma unroll
        for (int k = 0; k < QLEN; ++k)
            tg[k + 1] = tags[(s0 + k)*B_SZ + b];

        float acc = 0.f;
        int cnt = 0;
        if (q == 0) {
            const int t0  = tg[1];
            const int t0w = (t0 < 0) ? t0 + TP2 : t0;
            acc += trans[T_TAGS*TP2 + t0w];
        }
        #pragma unroll
        for (int k = 0; k < QLEN; ++k) {
            const int s = s0 + k;
            const int c = tg[k + 1];
            const float m = (c != PAD_I) ? 1.f : 0.f;
            cnt += (c != PAD_I) ? 1 : 0;
            if (s >= 1) {
                const int p  = tg[k];
                const int pw = (p < 0) ? p + TP2 : p;
                const int cw = (c < 0) ? c + TP2 : c;
                acc += trans[pw*TP2 + cw] * m;
            }
            if (s <= S_LEN - 2) {
                int cc = c; if (cc < 0) cc = 0;
                acc += em[((size_t)s*B_SZ + b)*T_TAGS + cc] * m;
            }
        }
        pl[q*B_SZ + b] = acc;
        pc[q*B_SZ + b] = cnt;
    }

    // ---------------- common tail: last-done block reduces ----------------
    __threadfence();
    int lf = 0;
    if (t == 0)
        lf = (atomicAdd(counter, 1u) == TOT_BLOCKS - 1) ? 1 : 0;
    lf = __shfl(lf, 0);
    if (lf) {
        __threadfence();   // acquire: see all blocks' pl/pc/denom stores
        float part = 0.f;
        #pragma unroll
        for (int bb = 0; bb < B_SZ / NTHR; ++bb) {
            const int b = bb * NTHR + t;
            float llh = 0.f;
            int cnt = 0;
            #pragma unroll
            for (int q = 0; q < NQ; ++q) {
                llh += pl[q*B_SZ + b];
                cnt += pc[q*B_SZ + b];
            }
            int li = cnt - 1; if (li < 0) li = 0;
            const int lt  = tags[li*B_SZ + b];
            const int ltw = (lt < 0) ? lt + TP2 : lt;
            llh += trans[ltw*TP2 + (T_TAGS + 1)];
            const float ml = (tags[(S_LEN - 1)*B_SZ + b] != PAD_I) ? 1.f : 0.f;
            int ltc = lt; if (ltc < 0) ltc = 0;
            llh += em[((size_t)(S_LEN - 1)*B_SZ + b)*T_TAGS + ltc] * ml;
            part += llh - denom_out[b];
        }
        #pragma unroll
        for (int off = 32; off; off >>= 1)
            part += __shfl_xor(part, off);
        if (t == 0)
            out[0] = part * (1.f / (float)B_SZ);
    }
}

extern "C" void kernel_launch(void* const* d_in, const int* in_sizes, int n_in,
                              void* d_out, int out_size, void* d_ws, size_t ws_size,
                              hipStream_t stream) {
    const float* em    = (const float*)d_in[0];
    const float* trans = (const float*)d_in[1];
    const int*   tags  = (const int*)d_in[2];
    float* out   = (float*)d_out;

    float* denom = (float*)d_ws;                         // 512 f
    float* pl    = denom + B_SZ;                         // NQ*512 f
    int*   pc    = (int*)(pl + NQ*B_SZ);                 // NQ*512 i
    unsigned int* counter = (unsigned int*)(pc + NQ*B_SZ);

    hipMemsetAsync(counter, 0, sizeof(unsigned int), stream);
    crf_main<<<TOT_BLOCKS, NTHR, 0, stream>>>(em, trans, tags, denom, pl, pc, counter, out);
}